// Round 4
// baseline (252.858 us; speedup 1.0000x reference)
//
#include <hip/hip_runtime.h>

// Problem constants
#define B_SZ   8
#define T_SEQ  2048
#define C_DIM  1024
#define H_DIM  128

typedef _Float16 half8   __attribute__((ext_vector_type(8)));
typedef _Float16 half4_t __attribute__((ext_vector_type(4)));
typedef float    f32x4   __attribute__((ext_vector_type(4)));

#define MFMA(a, b, c) __builtin_amdgcn_mfma_f32_16x16x32_f16(a, b, c, 0, 0, 0)

// ---------------------------------------------------------------------------
// prep: W [C][H] fp32 -> WT [H][C] half (3 weights).  grid (512,3) x 256
// ---------------------------------------------------------------------------
__global__ __launch_bounds__(256) void prep_kernel(
    const float* __restrict__ Wk, const float* __restrict__ Wq,
    const float* __restrict__ Wv, _Float16* __restrict__ WT_all)
{
    const int w = blockIdx.y;
    const float* W = (w == 0) ? Wk : (w == 1) ? Wq : Wv;
    _Float16* dst = WT_all + (size_t)w * (C_DIM * H_DIM);
    int tid = blockIdx.x * 256 + threadIdx.x;
    int c = tid >> 7;
    int h = tid & (H_DIM - 1);
    dst[(size_t)h * C_DIM + c] = (_Float16)W[tid];
}

// ---------------------------------------------------------------------------
// proj: out[m][n] = sum_k x[m][k]*W[k][n], M=16384 K=1024 N=128.
// grid (3,256) x 256 (4 waves, each 32m x 64n).   (unchanged from R3)
// w==0 -> k [B*T][H], w==1 -> q, w==2 -> vT [B][H][T] (transposed).
// ---------------------------------------------------------------------------
__global__ __launch_bounds__(256, 3) void proj_kernel(
    const float* __restrict__ x, const _Float16* __restrict__ WT_all,
    _Float16* __restrict__ q, _Float16* __restrict__ k, _Float16* __restrict__ vT)
{
    __shared__ _Float16 xs [64][72];
    __shared__ _Float16 wsh[128][72];

    const int w  = blockIdx.x;
    const int m0 = blockIdx.y * 64;
    const _Float16* WT = WT_all + (size_t)w * (C_DIM * H_DIM);

    const int t    = threadIdx.x;
    const int wave = t >> 6, lane = t & 63;
    const int quad = lane >> 4, l15 = lane & 15;
    const int wm = (wave >> 1) * 32;
    const int wn = (wave & 1) * 64;

    f32x4 acc[2][4] = {};

    for (int k0 = 0; k0 < C_DIM; k0 += 64) {
        __syncthreads();
        {
            const int row_ = t >> 4, col = (t & 15) * 4;
            #pragma unroll
            for (int p = 0; p < 4; ++p) {
                int row = p * 16 + row_;
                float4 f = *(const float4*)(x + (size_t)(m0 + row) * C_DIM + k0 + col);
                half4_t hv = { (_Float16)f.x, (_Float16)f.y, (_Float16)f.z, (_Float16)f.w };
                *(half4_t*)(&xs[row][col]) = hv;
            }
        }
        {
            const int row_ = t >> 3, col = (t & 7) * 8;
            #pragma unroll
            for (int p = 0; p < 4; ++p) {
                int row = p * 32 + row_;
                *(half8*)(&wsh[row][col]) = *(const half8*)(WT + (size_t)row * C_DIM + k0 + col);
            }
        }
        __syncthreads();
        #pragma unroll
        for (int kb = 0; kb < 2; ++kb) {
            half8 af[2], bf[4];
            #pragma unroll
            for (int i = 0; i < 2; ++i)
                af[i] = *(const half8*)(&xs[wm + i * 16 + l15][kb * 32 + quad * 8]);
            #pragma unroll
            for (int j = 0; j < 4; ++j)
                bf[j] = *(const half8*)(&wsh[wn + j * 16 + l15][kb * 32 + quad * 8]);
            #pragma unroll
            for (int i = 0; i < 2; ++i)
                #pragma unroll
                for (int j = 0; j < 4; ++j)
                    acc[i][j] = MFMA(af[i], bf[j], acc[i][j]);
        }
    }

    if (w != 2) {
        _Float16* outN = (w == 0) ? k : q;
        #pragma unroll
        for (int i = 0; i < 2; ++i) {
            int row = m0 + wm + i * 16 + quad * 4;
            #pragma unroll
            for (int j = 0; j < 4; ++j) {
                int col = wn + j * 16 + l15;
                #pragma unroll
                for (int r = 0; r < 4; ++r)
                    outN[(size_t)(row + r) * H_DIM + col] = (_Float16)acc[i][j][r];
            }
        }
    } else {
        #pragma unroll
        for (int i = 0; i < 2; ++i) {
            int grow = m0 + wm + i * 16 + quad * 4;
            int bb = grow >> 11, tp = grow & (T_SEQ - 1);
            #pragma unroll
            for (int j = 0; j < 4; ++j) {
                int h = wn + j * 16 + l15;
                half4_t hv = { (_Float16)acc[i][j][0], (_Float16)acc[i][j][1],
                               (_Float16)acc[i][j][2], (_Float16)acc[i][j][3] };
                *(half4_t*)(vT + ((size_t)bb * H_DIM + h) * T_SEQ + tp) = hv;
            }
        }
    }
}

// ---------------------------------------------------------------------------
// attn: 4 waves/block, qtile 64 (wave = 16-row strip), kv tile 64,
// kv-chunk = 4 tiles (256 keys). Units/batch = sum_{qt<32}(qt/4+1) = 144.
// Grid 1152: b = n&7 (XCD affinity), u = n>>3 decoded heavy-first (qt 31..0).
// K staged in LDS (shared by 4 waves); V read direct from global (L2-local).
// ps = per-wave float strip, stride 76 (conflict-free read/write).
// qt<=3 (single chunk) writes out directly; else partial (O half, m, l).
// ---------------------------------------------------------------------------
__global__ __launch_bounds__(256, 4) void attn_kernel(
    const _Float16* __restrict__ q, const _Float16* __restrict__ k,
    const _Float16* __restrict__ vT,
    _Float16* __restrict__ pO, float* __restrict__ ml, float* __restrict__ out)
{
    __shared__ _Float16 ks[64][136];     // 17408 B
    __shared__ float    ps[4][16][76];   // 19456 B

    const int n = blockIdx.x;
    const int b = n & 7;
    const int u = n >> 3;                // 0..143

    // decode u -> (qt, c), qt descending 31..0 (heavy units first)
    int qt = 31, c = 0;
    {
        int acc = 0;
        #pragma unroll 1
        while (true) {
            int nch = (qt >> 2) + 1;
            if (u < acc + nch) { c = u - acc; break; }
            acc += nch; --qt;
        }
    }
    const bool partial = (qt >= 4);

    const int kt0 = c * 4;
    const int kt1 = min(qt, c * 4 + 3);

    const int t = threadIdx.x;
    const int wave = t >> 6, lane = t & 63;
    const int quad = lane >> 4, l15 = lane & 15;
    const int qrow0 = qt * 64 + wave * 16;

    const _Float16* qb = q  + (size_t)b * T_SEQ * H_DIM;
    const _Float16* kp = k  + (size_t)b * T_SEQ * H_DIM;
    const _Float16* vp = vT + (size_t)b * H_DIM * T_SEQ;

    // Q fragments (A layout), pre-scaled by 1/sqrt(H)
    half8 aq[4];
    #pragma unroll
    for (int i = 0; i < 4; ++i) {
        half8 v = *(const half8*)(qb + (size_t)(qrow0 + l15) * H_DIM + i * 32 + quad * 8);
        #pragma unroll
        for (int j = 0; j < 8; ++j) v[j] = v[j] * (_Float16)0.088388347648318447f;
        aq[i] = v;
    }

    f32x4 accO[8] = {};
    float mrun[4], lrun[4];
    #pragma unroll
    for (int r = 0; r < 4; ++r) { mrun[r] = -3.0e38f; lrun[r] = 0.0f; }

    for (int kt = kt0; kt <= kt1; ++kt) {
        const int kv0 = kt * 64;
        __syncthreads();                      // protect ks reuse
        // stage K tile [64][128] (256 threads, 4 rows x 16 segs each pass)
        {
            const int row_ = t >> 4, seg = t & 15;
            #pragma unroll
            for (int p = 0; p < 4; ++p) {
                int row = p * 16 + row_;
                *(half8*)(&ks[row][seg * 8]) =
                    *(const half8*)(kp + (size_t)(kv0 + row) * H_DIM + seg * 8);
            }
        }
        __syncthreads();

        // S = Q K^T (Q pre-scaled)
        f32x4 sacc[4] = {};
        #pragma unroll
        for (int kbi = 0; kbi < 4; ++kbi) {
            #pragma unroll
            for (int nt = 0; nt < 4; ++nt) {
                half8 bf = *(const half8*)(&ks[nt * 16 + l15][kbi * 32 + quad * 8]);
                sacc[nt] = MFMA(aq[kbi], bf, sacc[nt]);
            }
        }

        // causal mask (diagonal-crossing tiles only; wave-specific)
        if (kv0 + 63 > qrow0) {
            #pragma unroll
            for (int nt = 0; nt < 4; ++nt) {
                int key = kv0 + nt * 16 + l15;
                #pragma unroll
                for (int r = 0; r < 4; ++r) {
                    int qr = qrow0 + quad * 4 + r;
                    if (key > qr) sacc[nt][r] = -1.0e30f;
                }
            }
        }

        // online softmax (row r spread over the 16 lanes of this quad group)
        float mnew[4], alpha[4], rsum[4];
        #pragma unroll
        for (int r = 0; r < 4; ++r) {
            float rm = fmaxf(fmaxf(sacc[0][r], sacc[1][r]), fmaxf(sacc[2][r], sacc[3][r]));
            rm = fmaxf(rm, __shfl_xor(rm, 1));
            rm = fmaxf(rm, __shfl_xor(rm, 2));
            rm = fmaxf(rm, __shfl_xor(rm, 4));
            rm = fmaxf(rm, __shfl_xor(rm, 8));
            mnew[r]  = fmaxf(mrun[r], rm);
            alpha[r] = __expf(mrun[r] - mnew[r]);
            mrun[r]  = mnew[r];
            rsum[r]  = 0.0f;
        }
        #pragma unroll
        for (int nt = 0; nt < 4; ++nt)
            #pragma unroll
            for (int r = 0; r < 4; ++r) {
                float p = __expf(sacc[nt][r] - mnew[r]);
                rsum[r] += p;
                ps[wave][quad * 4 + r][nt * 16 + l15] = p;   // C layout -> LDS (float)
            }
        #pragma unroll
        for (int r = 0; r < 4; ++r) {
            rsum[r] += __shfl_xor(rsum[r], 1);
            rsum[r] += __shfl_xor(rsum[r], 2);
            rsum[r] += __shfl_xor(rsum[r], 4);
            rsum[r] += __shfl_xor(rsum[r], 8);
            lrun[r] = lrun[r] * alpha[r] + rsum[r];
        }
        #pragma unroll
        for (int nt = 0; nt < 8; ++nt)
            #pragma unroll
            for (int r = 0; r < 4; ++r)
                accO[nt][r] *= alpha[r];

        // no barrier needed: per-wave ps strip, same-wave RAW (lgkmcnt)

        // O += P V : P back in A layout (float LDS -> cvt), V direct global
        f32x4 q0 = *(const f32x4*)(&ps[wave][l15][quad * 8]);
        f32x4 q1 = *(const f32x4*)(&ps[wave][l15][quad * 8 + 4]);
        f32x4 q2 = *(const f32x4*)(&ps[wave][l15][32 + quad * 8]);
        f32x4 q3 = *(const f32x4*)(&ps[wave][l15][32 + quad * 8 + 4]);
        half8 pf0, pf1;
        #pragma unroll
        for (int j = 0; j < 4; ++j) {
            pf0[j]     = (_Float16)q0[j];
            pf0[4 + j] = (_Float16)q1[j];
            pf1[j]     = (_Float16)q2[j];
            pf1[4 + j] = (_Float16)q3[j];
        }
        #pragma unroll
        for (int nt = 0; nt < 8; ++nt) {
            const _Float16* vrow = vp + (size_t)(nt * 16 + l15) * T_SEQ + kv0;
            half8 vf0 = *(const half8*)(vrow + quad * 8);
            half8 vf1 = *(const half8*)(vrow + 32 + quad * 8);
            accO[nt] = MFMA(pf0, vf0, accO[nt]);
            accO[nt] = MFMA(pf1, vf1, accO[nt]);
        }
    }

    if (partial) {
        const int pid = b * 140 + u;                  // u < 140 for qt>=4
        const int urow = wave * 16 + quad * 4;        // row within unit
        #pragma unroll
        for (int nt = 0; nt < 8; ++nt)
            #pragma unroll
            for (int r = 0; r < 4; ++r)
                pO[(size_t)pid * 8192 + (urow + r) * 128 + nt * 16 + l15]
                    = (_Float16)accO[nt][r];
        if (l15 == 0) {
            #pragma unroll
            for (int r = 0; r < 4; ++r) {
                ml[(size_t)pid * 128 + urow + r]      = mrun[r];
                ml[(size_t)pid * 128 + 64 + urow + r] = lrun[r];
            }
        }
    } else {
        float invl[4];
        #pragma unroll
        for (int r = 0; r < 4; ++r) invl[r] = 1.0f / lrun[r];
        #pragma unroll
        for (int nt = 0; nt < 8; ++nt)
            #pragma unroll
            for (int r = 0; r < 4; ++r)
                out[((size_t)b * T_SEQ + qrow0 + quad * 4 + r) * H_DIM + nt * 16 + l15]
                    = accO[nt][r] * invl[r];
    }
}

// ---------------------------------------------------------------------------
// combine: merge nc = qt/4+1 (2..8) chunk partials per 64-row strip (qt>=4).
// grid 224 (28 strips x 8 b) x 256.
// ---------------------------------------------------------------------------
__global__ __launch_bounds__(256) void attn_combine(
    const _Float16* __restrict__ pO, const float* __restrict__ ml,
    float* __restrict__ out)
{
    const int n = blockIdx.x;
    const int b = n & 7;
    const int qt = 4 + (n >> 3);          // 4..31
    const int nc = (qt >> 2) + 1;

    // u0 = units before qt in heavy-first order (qt descending)
    int u0 = 0;
    #pragma unroll 1
    for (int q2 = 31; q2 > qt; --q2) u0 += (q2 >> 2) + 1;
    const int pid0 = b * 140 + u0;

    const int t = threadIdx.x;
    __shared__ float wsc[8][64];

    if (t < 64) {
        float mv[8], lv[8];
        float M = -3.0e38f;
        for (int c = 0; c < nc; ++c) {
            mv[c] = ml[(size_t)(pid0 + c) * 128 + t];
            lv[c] = ml[(size_t)(pid0 + c) * 128 + 64 + t];
            M = fmaxf(M, mv[c]);
        }
        float denom = 0.0f;
        for (int c = 0; c < nc; ++c) {
            float wgt = __expf(mv[c] - M);
            denom += lv[c] * wgt;
            wsc[c][t] = wgt;
        }
        float inv = 1.0f / denom;
        for (int c = 0; c < nc; ++c) wsc[c][t] *= inv;
    }
    __syncthreads();

    const int h  = t & 127;
    const int rg = t >> 7;                // 0 or 1 -> rows rg*32..+31
    for (int rr = 0; rr < 32; ++rr) {
        int row = rg * 32 + rr;
        float acc = 0.0f;
        for (int c = 0; c < nc; ++c)
            acc += wsc[c][row] * (float)pO[(size_t)(pid0 + c) * 8192 + row * 128 + h];
        out[((size_t)b * T_SEQ + qt * 64 + row) * H_DIM + h] = acc;
    }
}

// ---------------------------------------------------------------------------
extern "C" void kernel_launch(void* const* d_in, const int* in_sizes, int n_in,
                              void* d_out, int out_size, void* d_ws, size_t ws_size,
                              hipStream_t stream)
{
    const float* x  = (const float*)d_in[0];
    const float* Wk = (const float*)d_in[1];
    const float* Wq = (const float*)d_in[2];
    const float* Wv = (const float*)d_in[3];
    float* out = (float*)d_out;

    _Float16* ws = (_Float16*)d_ws;
    const size_t NQKV = (size_t)B_SZ * T_SEQ * H_DIM;          // 2,097,152
    _Float16* q_ws  = ws;
    _Float16* k_ws  = ws + NQKV;
    _Float16* vT_ws = ws + 2 * NQKV;
    _Float16* wt_ws = ws + 3 * NQKV;                           // 3*C*H halfs
    _Float16* pO_ws = wt_ws + 3 * (size_t)(C_DIM * H_DIM);     // 1120 units * 8192 halfs
    float*    ml_ws = (float*)(pO_ws + (size_t)1120 * 8192);   // 1120 * 128 floats

    prep_kernel <<<dim3(512, 3), 256, 0, stream>>>(Wk, Wq, Wv, wt_ws);
    proj_kernel <<<dim3(3, 256), 256, 0, stream>>>(x, wt_ws, q_ws, k_ws, vT_ws);
    attn_kernel <<<1152, 256, 0, stream>>>(q_ws, k_ws, vT_ws, pO_ws, ml_ws, out);
    attn_combine<<<224, 256, 0, stream>>>(pO_ws, ml_ws, out);
}

// Round 5
// 189.882 us; speedup vs baseline: 1.3317x; 1.3317x over previous
//
#include <hip/hip_runtime.h>

// Problem constants
#define B_SZ   8
#define T_SEQ  2048
#define C_DIM  1024
#define H_DIM  128

typedef _Float16 half8   __attribute__((ext_vector_type(8)));
typedef _Float16 half4_t __attribute__((ext_vector_type(4)));
typedef float    f32x4   __attribute__((ext_vector_type(4)));

#define MFMA(a, b, c) __builtin_amdgcn_mfma_f32_16x16x32_f16(a, b, c, 0, 0, 0)

// ---------------------------------------------------------------------------
// prep: W [C][H] fp32 -> WT [H][C] half (3 weights).  grid (512,3) x 256
// ---------------------------------------------------------------------------
__global__ __launch_bounds__(256) void prep_kernel(
    const float* __restrict__ Wk, const float* __restrict__ Wq,
    const float* __restrict__ Wv, _Float16* __restrict__ WT_all)
{
    const int w = blockIdx.y;
    const float* W = (w == 0) ? Wk : (w == 1) ? Wq : Wv;
    _Float16* dst = WT_all + (size_t)w * (C_DIM * H_DIM);
    int tid = blockIdx.x * 256 + threadIdx.x;
    int c = tid >> 7;
    int h = tid & (H_DIM - 1);
    dst[(size_t)h * C_DIM + c] = (_Float16)W[tid];
}

// ---------------------------------------------------------------------------
// proj: out[m][n] = sum_k x[m][k]*W[k][n], M=16384 K=1024 N=128.
// grid (3,256) x 256 (4 waves, each 32m x 64n).   (unchanged)
// w==0 -> k [B*T][H], w==1 -> q, w==2 -> vT [B][H][T] (transposed).
// ---------------------------------------------------------------------------
__global__ __launch_bounds__(256, 3) void proj_kernel(
    const float* __restrict__ x, const _Float16* __restrict__ WT_all,
    _Float16* __restrict__ q, _Float16* __restrict__ k, _Float16* __restrict__ vT)
{
    __shared__ _Float16 xs [64][72];
    __shared__ _Float16 wsh[128][72];

    const int w  = blockIdx.x;
    const int m0 = blockIdx.y * 64;
    const _Float16* WT = WT_all + (size_t)w * (C_DIM * H_DIM);

    const int t    = threadIdx.x;
    const int wave = t >> 6, lane = t & 63;
    const int quad = lane >> 4, l15 = lane & 15;
    const int wm = (wave >> 1) * 32;
    const int wn = (wave & 1) * 64;

    f32x4 acc[2][4] = {};

    for (int k0 = 0; k0 < C_DIM; k0 += 64) {
        __syncthreads();
        {
            const int row_ = t >> 4, col = (t & 15) * 4;
            #pragma unroll
            for (int p = 0; p < 4; ++p) {
                int row = p * 16 + row_;
                float4 f = *(const float4*)(x + (size_t)(m0 + row) * C_DIM + k0 + col);
                half4_t hv = { (_Float16)f.x, (_Float16)f.y, (_Float16)f.z, (_Float16)f.w };
                *(half4_t*)(&xs[row][col]) = hv;
            }
        }
        {
            const int row_ = t >> 3, col = (t & 7) * 8;
            #pragma unroll
            for (int p = 0; p < 4; ++p) {
                int row = p * 32 + row_;
                *(half8*)(&wsh[row][col]) = *(const half8*)(WT + (size_t)row * C_DIM + k0 + col);
            }
        }
        __syncthreads();
        #pragma unroll
        for (int kb = 0; kb < 2; ++kb) {
            half8 af[2], bf[4];
            #pragma unroll
            for (int i = 0; i < 2; ++i)
                af[i] = *(const half8*)(&xs[wm + i * 16 + l15][kb * 32 + quad * 8]);
            #pragma unroll
            for (int j = 0; j < 4; ++j)
                bf[j] = *(const half8*)(&wsh[wn + j * 16 + l15][kb * 32 + quad * 8]);
            #pragma unroll
            for (int i = 0; i < 2; ++i)
                #pragma unroll
                for (int j = 0; j < 4; ++j)
                    acc[i][j] = MFMA(af[i], bf[j], acc[i][j]);
        }
    }

    if (w != 2) {
        _Float16* outN = (w == 0) ? k : q;
        #pragma unroll
        for (int i = 0; i < 2; ++i) {
            int row = m0 + wm + i * 16 + quad * 4;
            #pragma unroll
            for (int j = 0; j < 4; ++j) {
                int col = wn + j * 16 + l15;
                #pragma unroll
                for (int r = 0; r < 4; ++r)
                    outN[(size_t)(row + r) * H_DIM + col] = (_Float16)acc[i][j][r];
            }
        }
    } else {
        #pragma unroll
        for (int i = 0; i < 2; ++i) {
            int grow = m0 + wm + i * 16 + quad * 4;
            int bb = grow >> 11, tp = grow & (T_SEQ - 1);
            #pragma unroll
            for (int j = 0; j < 4; ++j) {
                int h = wn + j * 16 + l15;
                half4_t hv = { (_Float16)acc[i][j][0], (_Float16)acc[i][j][1],
                               (_Float16)acc[i][j][2], (_Float16)acc[i][j][3] };
                *(half4_t*)(vT + ((size_t)bb * H_DIM + h) * T_SEQ + tp) = hv;
            }
        }
    }
}

// ---------------------------------------------------------------------------
// attn: 4 waves/block, qtile 64, kv tile 64, kv-chunk 256. (unchanged)
// ---------------------------------------------------------------------------
__global__ __launch_bounds__(256, 4) void attn_kernel(
    const _Float16* __restrict__ q, const _Float16* __restrict__ k,
    const _Float16* __restrict__ vT,
    _Float16* __restrict__ pO, float* __restrict__ ml, float* __restrict__ out)
{
    __shared__ _Float16 ks[64][136];     // 17408 B
    __shared__ float    ps[4][16][76];   // 19456 B

    const int n = blockIdx.x;
    const int b = n & 7;
    const int u = n >> 3;                // 0..143

    int qt = 31, c = 0;
    {
        int acc = 0;
        #pragma unroll 1
        while (true) {
            int nch = (qt >> 2) + 1;
            if (u < acc + nch) { c = u - acc; break; }
            acc += nch; --qt;
        }
    }
    const bool partial = (qt >= 4);

    const int kt0 = c * 4;
    const int kt1 = min(qt, c * 4 + 3);

    const int t = threadIdx.x;
    const int wave = t >> 6, lane = t & 63;
    const int quad = lane >> 4, l15 = lane & 15;
    const int qrow0 = qt * 64 + wave * 16;

    const _Float16* qb = q  + (size_t)b * T_SEQ * H_DIM;
    const _Float16* kp = k  + (size_t)b * T_SEQ * H_DIM;
    const _Float16* vp = vT + (size_t)b * H_DIM * T_SEQ;

    half8 aq[4];
    #pragma unroll
    for (int i = 0; i < 4; ++i) {
        half8 v = *(const half8*)(qb + (size_t)(qrow0 + l15) * H_DIM + i * 32 + quad * 8);
        #pragma unroll
        for (int j = 0; j < 8; ++j) v[j] = v[j] * (_Float16)0.088388347648318447f;
        aq[i] = v;
    }

    f32x4 accO[8] = {};
    float mrun[4], lrun[4];
    #pragma unroll
    for (int r = 0; r < 4; ++r) { mrun[r] = -3.0e38f; lrun[r] = 0.0f; }

    for (int kt = kt0; kt <= kt1; ++kt) {
        const int kv0 = kt * 64;
        __syncthreads();
        {
            const int row_ = t >> 4, seg = t & 15;
            #pragma unroll
            for (int p = 0; p < 4; ++p) {
                int row = p * 16 + row_;
                *(half8*)(&ks[row][seg * 8]) =
                    *(const half8*)(kp + (size_t)(kv0 + row) * H_DIM + seg * 8);
            }
        }
        __syncthreads();

        f32x4 sacc[4] = {};
        #pragma unroll
        for (int kbi = 0; kbi < 4; ++kbi) {
            #pragma unroll
            for (int nt = 0; nt < 4; ++nt) {
                half8 bf = *(const half8*)(&ks[nt * 16 + l15][kbi * 32 + quad * 8]);
                sacc[nt] = MFMA(aq[kbi], bf, sacc[nt]);
            }
        }

        if (kv0 + 63 > qrow0) {
            #pragma unroll
            for (int nt = 0; nt < 4; ++nt) {
                int key = kv0 + nt * 16 + l15;
                #pragma unroll
                for (int r = 0; r < 4; ++r) {
                    int qr = qrow0 + quad * 4 + r;
                    if (key > qr) sacc[nt][r] = -1.0e30f;
                }
            }
        }

        float mnew[4], alpha[4], rsum[4];
        #pragma unroll
        for (int r = 0; r < 4; ++r) {
            float rm = fmaxf(fmaxf(sacc[0][r], sacc[1][r]), fmaxf(sacc[2][r], sacc[3][r]));
            rm = fmaxf(rm, __shfl_xor(rm, 1));
            rm = fmaxf(rm, __shfl_xor(rm, 2));
            rm = fmaxf(rm, __shfl_xor(rm, 4));
            rm = fmaxf(rm, __shfl_xor(rm, 8));
            mnew[r]  = fmaxf(mrun[r], rm);
            alpha[r] = __expf(mrun[r] - mnew[r]);
            mrun[r]  = mnew[r];
            rsum[r]  = 0.0f;
        }
        #pragma unroll
        for (int nt = 0; nt < 4; ++nt)
            #pragma unroll
            for (int r = 0; r < 4; ++r) {
                float p = __expf(sacc[nt][r] - mnew[r]);
                rsum[r] += p;
                ps[wave][quad * 4 + r][nt * 16 + l15] = p;
            }
        #pragma unroll
        for (int r = 0; r < 4; ++r) {
            rsum[r] += __shfl_xor(rsum[r], 1);
            rsum[r] += __shfl_xor(rsum[r], 2);
            rsum[r] += __shfl_xor(rsum[r], 4);
            rsum[r] += __shfl_xor(rsum[r], 8);
            lrun[r] = lrun[r] * alpha[r] + rsum[r];
        }
        #pragma unroll
        for (int nt = 0; nt < 8; ++nt)
            #pragma unroll
            for (int r = 0; r < 4; ++r)
                accO[nt][r] *= alpha[r];

        f32x4 q0 = *(const f32x4*)(&ps[wave][l15][quad * 8]);
        f32x4 q1 = *(const f32x4*)(&ps[wave][l15][quad * 8 + 4]);
        f32x4 q2 = *(const f32x4*)(&ps[wave][l15][32 + quad * 8]);
        f32x4 q3 = *(const f32x4*)(&ps[wave][l15][32 + quad * 8 + 4]);
        half8 pf0, pf1;
        #pragma unroll
        for (int j = 0; j < 4; ++j) {
            pf0[j]     = (_Float16)q0[j];
            pf0[4 + j] = (_Float16)q1[j];
            pf1[j]     = (_Float16)q2[j];
            pf1[4 + j] = (_Float16)q3[j];
        }
        #pragma unroll
        for (int nt = 0; nt < 8; ++nt) {
            const _Float16* vrow = vp + (size_t)(nt * 16 + l15) * T_SEQ + kv0;
            half8 vf0 = *(const half8*)(vrow + quad * 8);
            half8 vf1 = *(const half8*)(vrow + 32 + quad * 8);
            accO[nt] = MFMA(pf0, vf0, accO[nt]);
            accO[nt] = MFMA(pf1, vf1, accO[nt]);
        }
    }

    if (partial) {
        const int pid = b * 140 + u;
        const int urow = wave * 16 + quad * 4;
        #pragma unroll
        for (int nt = 0; nt < 8; ++nt)
            #pragma unroll
            for (int r = 0; r < 4; ++r)
                pO[(size_t)pid * 8192 + (urow + r) * 128 + nt * 16 + l15]
                    = (_Float16)accO[nt][r];
        if (l15 == 0) {
            #pragma unroll
            for (int r = 0; r < 4; ++r) {
                ml[(size_t)pid * 128 + urow + r]      = mrun[r];
                ml[(size_t)pid * 128 + 64 + urow + r] = lrun[r];
            }
        }
    } else {
        float invl[4];
        #pragma unroll
        for (int r = 0; r < 4; ++r) invl[r] = 1.0f / lrun[r];
        #pragma unroll
        for (int nt = 0; nt < 8; ++nt)
            #pragma unroll
            for (int r = 0; r < 4; ++r)
                out[((size_t)b * T_SEQ + qrow0 + quad * 4 + r) * H_DIM + nt * 16 + l15]
                    = accO[nt][r] * invl[r];
    }
}

// ---------------------------------------------------------------------------
// combine (REWRITTEN): one thread per (row, 8-wide h segment).
// grid 896 = (28 strips x 4 row-groups x 8 batches) x 256 threads.
// Per thread: nc half8 loads (independent, 16B) + redundant per-row weight
// calc from ml (L1-broadcast) -> 2 float4 stores. No LDS, no barrier.
// ---------------------------------------------------------------------------
__global__ __launch_bounds__(256) void attn_combine(
    const _Float16* __restrict__ pO, const float* __restrict__ ml,
    float* __restrict__ out)
{
    const int n  = blockIdx.x;
    const int b  = n & 7;
    const int m  = n >> 3;               // 0..111
    const int rg = m & 3;
    const int qt = 4 + (m >> 2);         // 4..31
    const int nc = (qt >> 2) + 1;        // 2..8

    // u0 = units before qt in heavy-first order (qt descending)
    int u0 = 0;
    #pragma unroll 1
    for (int q2 = 31; q2 > qt; --q2) u0 += (q2 >> 2) + 1;
    const size_t pid0 = (size_t)b * 140 + u0;

    const int t    = threadIdx.x;
    const int row  = rg * 16 + (t >> 4);   // row within 64-row unit
    const int h    = (t & 15) * 8;

    float w[8];
    {
        float mv[8], lv[8], M = -3.0e38f;
        #pragma unroll 1
        for (int c = 0; c < nc; ++c) {
            mv[c] = ml[(pid0 + c) * 128 + row];
            lv[c] = ml[(pid0 + c) * 128 + 64 + row];
            M = fmaxf(M, mv[c]);
        }
        float denom = 0.0f;
        #pragma unroll 1
        for (int c = 0; c < nc; ++c) {
            w[c] = __expf(mv[c] - M);
            denom += lv[c] * w[c];
        }
        float inv = 1.0f / denom;
        #pragma unroll 1
        for (int c = 0; c < nc; ++c) w[c] *= inv;
    }

    float acc[8] = {};
    #pragma unroll 1
    for (int c = 0; c < nc; ++c) {
        half8 po = *(const half8*)(pO + (pid0 + c) * 8192 + row * 128 + h);
        #pragma unroll
        for (int j = 0; j < 8; ++j) acc[j] += w[c] * (float)po[j];
    }

    float* op = out + ((size_t)b * T_SEQ + qt * 64 + row) * H_DIM + h;
    f32x4 o0 = { acc[0], acc[1], acc[2], acc[3] };
    f32x4 o1 = { acc[4], acc[5], acc[6], acc[7] };
    *(f32x4*)(op)     = o0;
    *(f32x4*)(op + 4) = o1;
}

// ---------------------------------------------------------------------------
extern "C" void kernel_launch(void* const* d_in, const int* in_sizes, int n_in,
                              void* d_out, int out_size, void* d_ws, size_t ws_size,
                              hipStream_t stream)
{
    const float* x  = (const float*)d_in[0];
    const float* Wk = (const float*)d_in[1];
    const float* Wq = (const float*)d_in[2];
    const float* Wv = (const float*)d_in[3];
    float* out = (float*)d_out;

    _Float16* ws = (_Float16*)d_ws;
    const size_t NQKV = (size_t)B_SZ * T_SEQ * H_DIM;          // 2,097,152
    _Float16* q_ws  = ws;
    _Float16* k_ws  = ws + NQKV;
    _Float16* vT_ws = ws + 2 * NQKV;
    _Float16* wt_ws = ws + 3 * NQKV;                           // 3*C*H halfs
    _Float16* pO_ws = wt_ws + 3 * (size_t)(C_DIM * H_DIM);     // 1120 units * 8192 halfs
    float*    ml_ws = (float*)(pO_ws + (size_t)1120 * 8192);   // 1120 * 128 floats

    prep_kernel <<<dim3(512, 3), 256, 0, stream>>>(Wk, Wq, Wv, wt_ws);
    proj_kernel <<<dim3(3, 256), 256, 0, stream>>>(x, wt_ws, q_ws, k_ws, vT_ws);
    attn_kernel <<<1152, 256, 0, stream>>>(q_ws, k_ws, vT_ws, pO_ws, ml_ws, out);
    attn_combine<<<896, 256, 0, stream>>>(pO_ws, ml_ws, out);
}